// Round 12
// baseline (846.475 us; speedup 1.0000x reference)
//
#include <hip/hip_runtime.h>

#define NN 100000
#define NE 1600000
#define DD 128

typedef short short8 __attribute__((ext_vector_type(8)));
typedef float f32x4 __attribute__((ext_vector_type(4)));

// ---------------- bf16 helpers ----------------

__device__ __forceinline__ unsigned short f2bf(float f) {
    union { float f; unsigned u; } v; v.f = f;
    unsigned r = v.u + 0x7FFF + ((v.u >> 16) & 1);  // round-to-nearest-even
    return (unsigned short)(r >> 16);
}
__device__ __forceinline__ float bf2f(unsigned short b) {
    union { unsigned u; float f; } v; v.u = (unsigned)b << 16;
    return v.f;
}

// ---------------- CSR construction (padded: each node's range is a multiple of 8) ----------------

__global__ __launch_bounds__(256) void k_count(const int* __restrict__ dstA,
                                               int* __restrict__ cnt, int E) {
    int i = blockIdx.x * 256 + threadIdx.x;
    if (i < E) atomicAdd(&cnt[dstA[i]], 1);
}

__global__ __launch_bounds__(256) void k_dinv(const int* __restrict__ cnt,
                                              float* __restrict__ dinv, int N) {
    int n = blockIdx.x * 256 + threadIdx.x;
    if (n < N) dinv[n] = rsqrtf(2.0f + (float)cnt[n]);  // self-loop weight 2.0
}

// scan over PADDED counts -> rowpad
__global__ __launch_bounds__(256) void k_scan1(const int* __restrict__ cnt,
                                               int* __restrict__ rowpad,
                                               int* __restrict__ bsum, int N) {
    __shared__ int sm[256];
    int tid = threadIdx.x;
    int i = blockIdx.x * 256 + tid;
    int v = (i < N) ? ((cnt[i] + 7) & ~7) : 0;
    sm[tid] = v;
    #pragma unroll
    for (int off = 1; off < 256; off <<= 1) {
        __syncthreads();
        int t = (tid >= off) ? sm[tid - off] : 0;
        __syncthreads();
        sm[tid] += t;
    }
    if (i < N) rowpad[1 + i] = sm[tid];
    if (tid == 255) bsum[blockIdx.x] = sm[255];
}

__global__ __launch_bounds__(512) void k_scan2(int* __restrict__ bsum, int nb) {
    __shared__ int sm[512];
    int tid = threadIdx.x;
    sm[tid] = (tid < nb) ? bsum[tid] : 0;
    #pragma unroll
    for (int off = 1; off < 512; off <<= 1) {
        __syncthreads();
        int t = (tid >= off) ? sm[tid - off] : 0;
        __syncthreads();
        sm[tid] += t;
    }
    if (tid < nb) bsum[tid] = sm[tid];
}

// finalize rowpad; emit per-bucket (128 nodes) start cursors for the partition pass
__global__ __launch_bounds__(256) void k_scan3(int* __restrict__ rowpad,
                                               const int* __restrict__ bsum,
                                               int* __restrict__ bcur, int N) {
    int tid = threadIdx.x;
    int i = blockIdx.x * 256 + tid;
    if (i >= N) return;
    int add = (blockIdx.x > 0) ? bsum[blockIdx.x - 1] : 0;
    int fin = rowpad[1 + i] + add;
    rowpad[1 + i] = fin;
    if (i == 0) { rowpad[0] = 0; bcur[0] = 0; }
    if (((i + 1) & 127) == 0 && (i + 1) < N) bcur[(i + 1) >> 7] = fin;
}

// phase 1: chunked bucketing with block-aggregated atomics.
__global__ __launch_bounds__(256) void k_part(const int* __restrict__ srcA,
                                              const int* __restrict__ dstA,
                                              int* __restrict__ bcur,
                                              uint2* __restrict__ tmp, int E, int NBk) {
    __shared__ int cur[1024];
    int tid = threadIdx.x;
    int chunk = (E + gridDim.x - 1) / gridDim.x;
    int e0 = blockIdx.x * chunk;
    int e1 = e0 + chunk; e1 = e1 < E ? e1 : E;
    if (e0 >= e1) return;

    for (int b = tid; b < NBk; b += 256) cur[b] = 0;
    __syncthreads();
    for (int i = e0 + tid; i < e1; i += 256)
        atomicAdd(&cur[dstA[i] >> 7], 1);
    __syncthreads();
    for (int b = tid; b < NBk; b += 256) {
        int c = cur[b];
        cur[b] = (c > 0) ? atomicAdd(&bcur[b], c) : 0;
    }
    __syncthreads();
    for (int i = e0 + tid; i < e1; i += 256) {
        int s = srcA[i], d = dstA[i];
        int slot = atomicAdd(&cur[d >> 7], 1);
        uint2 p; p.x = (unsigned)s; p.y = (unsigned)d;
        tmp[slot] = p;
    }
}

// phase 2: exact padded-CSR placement; meta[e] = (src<<15) | bf16_nosign(dinv[src]).
// pad slots get 0 (node 0, weight +0.0).
__global__ __launch_bounds__(256) void k_place(const uint2* __restrict__ tmp,
                                               const int* __restrict__ rowpad,
                                               const int* __restrict__ cnt,
                                               const float* __restrict__ dinv,
                                               unsigned* __restrict__ meta, int N) {
    __shared__ int lcur[128];
    __shared__ int bcnt;
    int b = blockIdx.x;
    int n0 = b << 7;
    int tid = threadIdx.x;
    int base = rowpad[n0];
    if (tid == 0) bcnt = 0;
    __syncthreads();
    if (tid < 128) {
        int node = n0 + tid;
        if (node < N) {
            int st = rowpad[node], en = rowpad[node + 1];
            int rc = cnt[node];
            lcur[tid] = st - base;
            atomicAdd(&bcnt, rc);
            for (int p = st + rc; p < en; ++p) meta[p] = 0u;  // pads (<8 per node)
        } else {
            lcur[tid] = 0;
        }
    }
    __syncthreads();
    int cb = bcnt;
    for (int i = tid; i < cb; i += 256) {
        uint2 p = tmp[base + i];
        int j = (int)p.y - n0;
        int slot = atomicAdd(&lcur[j], 1);
        unsigned wb = (unsigned)f2bf(dinv[(int)p.x]) & 0x7fffu;
        meta[base + slot] = (p.x << 15) | wb;
    }
}

// ---------------- W preparation: fp32 W[k][n] -> global swizzled bf16 hi/lo ----------------
__global__ __launch_bounds__(256) void k_prep(const float* __restrict__ W,
                                              unsigned short* __restrict__ wt) {
    int idx = blockIdx.x * 256 + threadIdx.x;   // 0..16383
    char* hiB = (char*)wt;
    char* loB = (char*)wt + 32768;
    int k = idx >> 7, n = idx & 127;
    float w = W[idx];
    unsigned u = __float_as_uint(w);
    unsigned short hi = (unsigned short)(u >> 16);            // truncate
    float lof = w - __uint_as_float((unsigned)hi << 16);      // exact residual
    unsigned short lo = f2bf(lof);                            // rte
    int ba = (n * 256 + 2 * k) ^ ((n & 7) << 4);
    *(unsigned short*)(hiB + ba) = hi;
    *(unsigned short*)(loB + ba) = lo;
}

// ---------------- dense transform: Hs = bf16(F @ W) in SLICE-MAJOR layout ----------------
// Hs[slice][node][16ch]; slice = 16 channels = one XCD's L2-resident block (3.2MB).
__global__ __launch_bounds__(512) void k_gemm(const float* __restrict__ F,
                                              const unsigned short* __restrict__ wt,
                                              unsigned short* __restrict__ Hs, int N) {
    __shared__ char Wl[65536];  // [0,32K) hi, [32K,64K) lo, swizzled; reused for epilogue
    int tid = threadIdx.x;

    {
        const uint4* src = reinterpret_cast<const uint4*>(wt);
        uint4* dst = reinterpret_cast<uint4*>(Wl);
        #pragma unroll
        for (int i = 0; i < 8; ++i) dst[tid + 512 * i] = src[tid + 512 * i];
    }
    __syncthreads();

    int wv = tid >> 6;       // wave 0..7
    int l  = tid & 63;
    int nn = l & 15;         // A row / B col / D col within tile
    int g  = l >> 4;         // k-subgroup (and D row group)
    int r0w = blockIdx.x * 128 + wv * 16;

    int row = r0w + nn;
    row = row < N ? row : N - 1;  // clamp (stores guarded)
    const float4* Fr = reinterpret_cast<const float4*>(&F[(size_t)row * DD]);

    f32x4 acc[8];
    #pragma unroll
    for (int nt = 0; nt < 8; ++nt) acc[nt] = (f32x4){0.f, 0.f, 0.f, 0.f};

    #pragma unroll
    for (int ks = 0; ks < 4; ++ks) {
        float4 f0 = Fr[ks * 8 + g * 2];
        float4 f1 = Fr[ks * 8 + g * 2 + 1];
        short8 a;
        a[0] = (short)f2bf(f0.x); a[1] = (short)f2bf(f0.y);
        a[2] = (short)f2bf(f0.z); a[3] = (short)f2bf(f0.w);
        a[4] = (short)f2bf(f1.x); a[5] = (short)f2bf(f1.y);
        a[6] = (short)f2bf(f1.z); a[7] = (short)f2bf(f1.w);
        #pragma unroll
        for (int nt = 0; nt < 8; ++nt) {
            int ba = ((nt * 16 + nn) * 256 + ks * 64 + g * 16) ^ ((nn & 7) << 4);
            short8 bhi = *(const short8*)(Wl + ba);
            short8 blo = *(const short8*)(Wl + 32768 + ba);
            acc[nt] = __builtin_amdgcn_mfma_f32_16x16x32_bf16(a, blo, acc[nt], 0, 0, 0);
            acc[nt] = __builtin_amdgcn_mfma_f32_16x16x32_bf16(a, bhi, acc[nt], 0, 0, 0);
        }
    }

    __syncthreads();  // all waves done reading W -> Wl reusable

    // stage D tile into LDS: row stride 272B
    #pragma unroll
    for (int nt = 0; nt < 8; ++nt) {
        #pragma unroll
        for (int j = 0; j < 4; ++j) {
            int r = wv * 16 + 4 * g + j;
            *(unsigned short*)(Wl + r * 272 + (nt * 16 + nn) * 2) = f2bf(acc[nt][j]);
        }
    }
    __syncthreads();

    // slice-major writeback: 2048 16B chunks = 8 slices x 128 rows x 2 halves
    #pragma unroll
    for (int it = 0; it < 4; ++it) {
        int c = it * 512 + tid;
        int s = c >> 8;
        int r = (c >> 1) & 127;
        int half = c & 1;
        int gr = blockIdx.x * 128 + r;
        if (gr < N) {
            uint4 v = *(const uint4*)(Wl + r * 272 + s * 32 + half * 16);
            *reinterpret_cast<uint4*>(&Hs[(size_t)s * N * 16 + (size_t)gr * 16 + half * 8]) = v;
        }
    }
}

// ---------------- aggregation (XCD-sliced) ----------------
// grid = ceil(N/64)*8 blocks; slice s = blockIdx&7 -> XCD s (round-robin dispatch).
// Block: 4 waves x 16 nodes. Lane = edge-slot(8) x channel-pair(8).
// OUT[n][s*16+2p..] = dinv[n]*sum_e w[e]*Hs[s][src][2p..] + 2*dinv^2*Hs[s][n][2p..] + b + F (+X)

__global__ __launch_bounds__(256) void k_agg(const unsigned short* __restrict__ Hsall,
                                             const int* __restrict__ rowpad,
                                             const unsigned* __restrict__ meta,
                                             const float* __restrict__ dinv,
                                             const float* __restrict__ bias,
                                             const float* __restrict__ F,
                                             const float* __restrict__ X,
                                             float* __restrict__ OUT, int N, int addX) {
    int s = blockIdx.x & 7;
    int g = blockIdx.x >> 3;
    int wv = threadIdx.x >> 6;
    int lane = threadIdx.x & 63;
    int eg = lane >> 3;          // edge slot 0..7
    int p  = lane & 7;           // channel pair 0..7
    const char* hsB = (const char*)(Hsall + (size_t)s * N * 16);
    unsigned p4 = (unsigned)(p * 4);
    int cb = s * 16 + p * 2;
    float2 bvv = *reinterpret_cast<const float2*>(&bias[cb]);

    int n0 = g * 64 + wv * 16;
    int n1 = n0 + 16; if (n1 > N) n1 = N;
    for (int n = n0; n < n1; ++n) {
        int e = rowpad[n], e1 = rowpad[n + 1];
        float a0 = 0.f, a1 = 0.f;
        if (e < e1) {
            unsigned m = meta[e + eg];
            while (true) {
                unsigned node = m >> 15;
                float w = __uint_as_float((m << 16) & 0x7fff0000u);
                unsigned gv = *reinterpret_cast<const unsigned*>(hsB + ((size_t)node * 32 + p4));
                bool more = (e + 8) < e1;
                unsigned m2 = 0;
                if (more) m2 = meta[e + 8 + eg];
                a0 += w * __uint_as_float(gv << 16);
                a1 += w * __uint_as_float(gv & 0xffff0000u);
                if (!more) break;
                m = m2; e += 8;
            }
        }
        a0 += __shfl_xor(a0, 8, 64);  a1 += __shfl_xor(a1, 8, 64);
        a0 += __shfl_xor(a0, 16, 64); a1 += __shfl_xor(a1, 16, 64);
        a0 += __shfl_xor(a0, 32, 64); a1 += __shfl_xor(a1, 32, 64);
        if (eg == 0) {
            float di = dinv[n];
            float s2 = 2.f * di * di;
            unsigned hv = *reinterpret_cast<const unsigned*>(hsB + ((size_t)n * 32 + p4));
            size_t fb = (size_t)n * DD + cb;
            float2 fv = *reinterpret_cast<const float2*>(&F[fb]);
            float ox = di * a0 + s2 * __uint_as_float(hv << 16)         + bvv.x + fv.x;
            float oy = di * a1 + s2 * __uint_as_float(hv & 0xffff0000u) + bvv.y + fv.y;
            if (addX) {
                float2 xv = *reinterpret_cast<const float2*>(&X[fb]);
                ox += xv.x; oy += xv.y;
            }
            float2 o; o.x = ox; o.y = oy;
            *reinterpret_cast<float2*>(&OUT[fb]) = o;
        }
    }
}

// ---------------- launch ----------------

extern "C" void kernel_launch(void* const* d_in, const int* in_sizes, int n_in,
                              void* d_out, int out_size, void* d_ws, size_t ws_size,
                              hipStream_t stream) {
    const float* x  = (const float*)d_in[0];
    const int*   ei = (const int*)d_in[1];
    const float* W0 = (const float*)d_in[2];
    const float* b0 = (const float*)d_in[3];
    const float* W1 = (const float*)d_in[4];
    const float* b1 = (const float*)d_in[5];
    const float* W2 = (const float*)d_in[6];
    const float* b2 = (const float*)d_in[7];
    float* out = (float*)d_out;

    const int N = NN, E = NE;
    const int EPAD = NE + 8 * NN;  // padded edge-count upper bound (2.4M)
    const int* srcA = ei;       // edge_index[0]
    const int* dstA = ei + E;   // edge_index[1]

    char* ws = (char*)d_ws;
    size_t off = 0;
    auto alloc = [&](size_t bytes) -> char* {
        char* p = ws + off;
        off += (bytes + 255) & ~size_t(255);
        return p;
    };
    int*      rowpad = (int*)     alloc((size_t)(N + 1) * sizeof(int));
    int*      cnt    = (int*)     alloc((size_t)N * sizeof(int));
    int*      bcur   = (int*)     alloc(1024 * sizeof(int));
    int*      bsum   = (int*)     alloc(512 * sizeof(int));
    float*    dinv   = (float*)   alloc((size_t)N * sizeof(float));
    unsigned* meta   = (unsigned*)alloc((size_t)EPAD * sizeof(unsigned));
    unsigned short* wt0 = (unsigned short*)alloc(65536);
    unsigned short* wt1 = (unsigned short*)alloc(65536);
    unsigned short* wt2 = (unsigned short*)alloc(65536);
    // tmp (k_part/k_place only) and Hs (gemm/agg only) never live at the same time
    size_t tmpBytes = (size_t)EPAD * sizeof(uint2);
    size_t hBytes   = (size_t)N * DD * sizeof(unsigned short);
    char*  uni = alloc(tmpBytes > hBytes ? tmpBytes : hBytes);
    uint2* tmp = (uint2*)uni;
    unsigned short* h = (unsigned short*)uni;
    (void)ws_size; (void)in_sizes; (void)n_in; (void)out_size;

    hipMemsetAsync(cnt, 0, (size_t)N * sizeof(int), stream);

    int gE = (E + 255) / 256;     // 6250
    int gN = (N + 255) / 256;     // 391
    int NB = (N + 127) / 128;     // 782 buckets
    k_count<<<gE, 256, 0, stream>>>(dstA, cnt, E);
    k_prep <<<64, 256, 0, stream>>>(W0, wt0);
    k_prep <<<64, 256, 0, stream>>>(W1, wt1);
    k_prep <<<64, 256, 0, stream>>>(W2, wt2);
    k_dinv <<<gN, 256, 0, stream>>>(cnt, dinv, N);
    k_scan1<<<gN, 256, 0, stream>>>(cnt, rowpad, bsum, N);
    k_scan2<<<1, 512, 0, stream>>>(bsum, gN);
    k_scan3<<<gN, 256, 0, stream>>>(rowpad, bsum, bcur, N);
    k_part <<<256, 256, 0, stream>>>(srcA, dstA, bcur, tmp, E, NB);
    k_place<<<NB, 256, 0, stream>>>(tmp, rowpad, cnt, dinv, meta, N);

    int gG = (N + 127) / 128;        // 782
    int gA = ((N + 63) / 64) * 8;    // 12504 (multiple of 8 -> slice->XCD stable)

    // layer 0: F = x -> out
    k_gemm<<<gG, 512, 0, stream>>>(x, wt0, h, N);
    k_agg <<<gA, 256, 0, stream>>>(h, rowpad, meta, dinv, b0, x, nullptr, out, N, 0);
    // layer 1: F = out -> out (in-place safe: each row read only by its own wave)
    k_gemm<<<gG, 512, 0, stream>>>(out, wt1, h, N);
    k_agg <<<gA, 256, 0, stream>>>(h, rowpad, meta, dinv, b1, out, nullptr, out, N, 0);
    // layer 2: F = out -> out, plus global residual x
    k_gemm<<<gG, 512, 0, stream>>>(out, wt2, h, N);
    k_agg <<<gA, 256, 0, stream>>>(h, rowpad, meta, dinv, b2, out, x, out, N, 1);
}

// Round 13
// 404.692 us; speedup vs baseline: 2.0917x; 2.0917x over previous
//
#include <hip/hip_runtime.h>

#define NN 100000
#define NE 1600000
#define DD 128

typedef short short8 __attribute__((ext_vector_type(8)));
typedef float f32x4 __attribute__((ext_vector_type(4)));

// ---------------- bf16 helpers ----------------

__device__ __forceinline__ unsigned short f2bf(float f) {
    union { float f; unsigned u; } v; v.f = f;
    unsigned r = v.u + 0x7FFF + ((v.u >> 16) & 1);  // round-to-nearest-even
    return (unsigned short)(r >> 16);
}
__device__ __forceinline__ float bf2f(unsigned short b) {
    union { unsigned u; float f; } v; v.u = (unsigned)b << 16;
    return v.f;
}

// ---------------- CSR construction ----------------

__global__ __launch_bounds__(256) void k_count(const int* __restrict__ dstA,
                                               int* __restrict__ cnt, int E) {
    int i = blockIdx.x * 256 + threadIdx.x;
    if (i < E) atomicAdd(&cnt[dstA[i]], 1);
}

__global__ __launch_bounds__(256) void k_dinv(const int* __restrict__ rowp,
                                              float* __restrict__ dinv, int N) {
    int n = blockIdx.x * 256 + threadIdx.x;
    if (n < N) dinv[n] = rsqrtf(2.0f + (float)rowp[n + 1]);  // self-loop weight 2.0
}

__global__ __launch_bounds__(256) void k_scan1(int* __restrict__ rowp,
                                               int* __restrict__ bsum, int N) {
    __shared__ int sm[256];
    int tid = threadIdx.x;
    int i = blockIdx.x * 256 + tid;
    int v = (i < N) ? rowp[1 + i] : 0;
    sm[tid] = v;
    #pragma unroll
    for (int off = 1; off < 256; off <<= 1) {
        __syncthreads();
        int t = (tid >= off) ? sm[tid - off] : 0;
        __syncthreads();
        sm[tid] += t;
    }
    if (i < N) rowp[1 + i] = sm[tid];
    if (tid == 255) bsum[blockIdx.x] = sm[255];
}

__global__ __launch_bounds__(512) void k_scan2(int* __restrict__ bsum, int nb) {
    __shared__ int sm[512];
    int tid = threadIdx.x;
    sm[tid] = (tid < nb) ? bsum[tid] : 0;
    #pragma unroll
    for (int off = 1; off < 512; off <<= 1) {
        __syncthreads();
        int t = (tid >= off) ? sm[tid - off] : 0;
        __syncthreads();
        sm[tid] += t;
    }
    if (tid < nb) bsum[tid] = sm[tid];
}

// finalize rowp; emit per-bucket (128 nodes) start cursors for the partition pass
__global__ __launch_bounds__(256) void k_scan3(int* __restrict__ rowp,
                                               const int* __restrict__ bsum,
                                               int* __restrict__ bcur, int N) {
    int tid = threadIdx.x;
    int i = blockIdx.x * 256 + tid;
    if (i >= N) return;
    int add = (blockIdx.x > 0) ? bsum[blockIdx.x - 1] : 0;
    int fin = rowp[1 + i] + add;
    rowp[1 + i] = fin;
    if (i == 0) bcur[0] = 0;
    if (((i + 1) & 127) == 0 && (i + 1) < N) bcur[(i + 1) >> 7] = fin;
}

// phase 1: chunked bucketing with block-aggregated atomics.
__global__ __launch_bounds__(256) void k_part(const int* __restrict__ srcA,
                                              const int* __restrict__ dstA,
                                              int* __restrict__ bcur,
                                              uint2* __restrict__ tmp, int E, int NBk) {
    __shared__ int cur[1024];
    int tid = threadIdx.x;
    int chunk = (E + gridDim.x - 1) / gridDim.x;
    int e0 = blockIdx.x * chunk;
    int e1 = e0 + chunk; e1 = e1 < E ? e1 : E;
    if (e0 >= e1) return;

    for (int b = tid; b < NBk; b += 256) cur[b] = 0;
    __syncthreads();
    for (int i = e0 + tid; i < e1; i += 256)
        atomicAdd(&cur[dstA[i] >> 7], 1);
    __syncthreads();
    for (int b = tid; b < NBk; b += 256) {
        int c = cur[b];
        cur[b] = (c > 0) ? atomicAdd(&bcur[b], c) : 0;
    }
    __syncthreads();
    for (int i = e0 + tid; i < e1; i += 256) {
        int s = srcA[i], d = dstA[i];
        int slot = atomicAdd(&cur[d >> 7], 1);
        uint2 p; p.x = (unsigned)s; p.y = (unsigned)d;
        tmp[slot] = p;
    }
}

// phase 2: exact CSR placement within each bucket via LDS cursors
__global__ __launch_bounds__(256) void k_place(const uint2* __restrict__ tmp,
                                               const int* __restrict__ rowp,
                                               int* __restrict__ col, int N) {
    __shared__ int lcur[128];
    int b = blockIdx.x;
    int n0 = b << 7;
    int tid = threadIdx.x;
    int nEnd = n0 + 128; nEnd = nEnd < N ? nEnd : N;
    int base = rowp[n0];
    int cnt = rowp[nEnd] - base;
    if (tid < 128) {
        int node = n0 + tid;
        lcur[tid] = (node < N) ? (rowp[node] - base) : 0;
    }
    __syncthreads();
    for (int i = tid; i < cnt; i += 256) {
        uint2 p = tmp[base + i];
        int j = (int)p.y - n0;
        int slot = atomicAdd(&lcur[j], 1);
        col[base + slot] = (int)p.x;
    }
}

// ---------------- W preparation: fp32 W[k][n] -> global swizzled bf16 (all 3 layers) ----------------
// per layer 32KB; byte addr = (n*256 + 2k) ^ ((n&7)<<4); layer = blockIdx>>6
__global__ __launch_bounds__(256) void k_prep(const float* __restrict__ W0,
                                              const float* __restrict__ W1,
                                              const float* __restrict__ W2,
                                              unsigned short* __restrict__ wt) {
    int layer = blockIdx.x >> 6;
    int idx = (blockIdx.x & 63) * 256 + threadIdx.x;   // 0..16383
    const float* W = (layer == 0) ? W0 : (layer == 1) ? W1 : W2;
    char* dstB = (char*)(wt + (size_t)layer * 16384);
    int k = idx >> 7, n = idx & 127;
    int ba = (n * 256 + 2 * k) ^ ((n & 7) << 4);
    *(unsigned short*)(dstB + ba) = f2bf(W[idx]);
}

// ---------------- dense transform: Hb = bf16(bf16(F) @ bf16(W)), MFMA ----------------
// block = 512 (8 waves); wave w computes rows [blk*128 + w*16, +16) x 128 cols.
// LDS 34816B: [0,32KB) swizzled W during MFMA; reused as [128][272B] bf16 D-tile for epilogue.

__global__ __launch_bounds__(512) void k_gemm(const float* __restrict__ F,
                                              const unsigned short* __restrict__ wt,
                                              unsigned short* __restrict__ Hb, int N) {
    __shared__ char Wl[34816];
    int tid = threadIdx.x;

    {   // stage 32KB (2048 uint4), 4 per thread
        const uint4* src = reinterpret_cast<const uint4*>(wt);
        uint4* dst = reinterpret_cast<uint4*>(Wl);
        #pragma unroll
        for (int i = 0; i < 4; ++i) dst[tid + 512 * i] = src[tid + 512 * i];
    }
    __syncthreads();

    int wv = tid >> 6;       // wave 0..7
    int l  = tid & 63;
    int nn = l & 15;         // A row / B col / D col within tile
    int g  = l >> 4;         // k-subgroup (and D row group)
    int r0w = blockIdx.x * 128 + wv * 16;

    int row = r0w + nn;
    row = row < N ? row : N - 1;  // clamp (stores guarded)
    const float4* Fr = reinterpret_cast<const float4*>(&F[(size_t)row * DD]);

    f32x4 acc[8];
    #pragma unroll
    for (int nt = 0; nt < 8; ++nt) acc[nt] = (f32x4){0.f, 0.f, 0.f, 0.f};

    #pragma unroll
    for (int ks = 0; ks < 4; ++ks) {
        float4 f0 = Fr[ks * 8 + g * 2];
        float4 f1 = Fr[ks * 8 + g * 2 + 1];
        short8 a;
        a[0] = (short)f2bf(f0.x); a[1] = (short)f2bf(f0.y);
        a[2] = (short)f2bf(f0.z); a[3] = (short)f2bf(f0.w);
        a[4] = (short)f2bf(f1.x); a[5] = (short)f2bf(f1.y);
        a[6] = (short)f2bf(f1.z); a[7] = (short)f2bf(f1.w);
        #pragma unroll
        for (int nt = 0; nt < 8; ++nt) {
            int ba = ((nt * 16 + nn) * 256 + ks * 64 + g * 16) ^ ((nn & 7) << 4);
            short8 b = *(const short8*)(Wl + ba);
            acc[nt] = __builtin_amdgcn_mfma_f32_16x16x32_bf16(a, b, acc[nt], 0, 0, 0);
        }
    }

    __syncthreads();  // all waves done reading W -> Wl reusable

    // stage D tile into LDS: row stride 272B (rotates banks by 4/row)
    #pragma unroll
    for (int nt = 0; nt < 8; ++nt) {
        #pragma unroll
        for (int j = 0; j < 4; ++j) {
            int r = wv * 16 + 4 * g + j;
            *(unsigned short*)(Wl + r * 272 + (nt * 16 + nn) * 2) = f2bf(acc[nt][j]);
        }
    }
    __syncthreads();

    // coalesced writeback: 2048 uint4 chunks (128 rows x 16 chunks), 4 per thread
    #pragma unroll
    for (int it = 0; it < 4; ++it) {
        int idx = it * 512 + tid;
        int r = idx >> 4, ch = idx & 15;
        int gr = blockIdx.x * 128 + r;
        if (gr < N) {
            uint4 v = *(const uint4*)(Wl + r * 272 + ch * 16);
            *reinterpret_cast<uint4*>(&Hb[(size_t)gr * DD + ch * 8]) = v;
        }
    }
}

// ---------------- aggregation (round-5 verbatim: best measured 81.7us) ----------------
// OUT[n] = dinv[n] * sum_e dinv[col[e]]*Hb[col[e]] + 2*dinv[n]^2*Hb[n] + b + F[n] (+X[n])
// one wave per node; lane handles 2 channels (1x uint = 2x bf16) -> 256B coalesced row gathers.

__global__ __launch_bounds__(256) void k_agg(const unsigned short* __restrict__ Hb,
                                             const int* __restrict__ rowp,
                                             const int* __restrict__ col,
                                             const float* __restrict__ dinv,
                                             const float* __restrict__ bias,
                                             const float* __restrict__ F,
                                             const float* __restrict__ X,
                                             float* __restrict__ OUT, int N, int addX) {
    int lane = threadIdx.x & 63;
    int n = (blockIdx.x << 2) + (threadIdx.x >> 6);
    if (n >= N) return;
    int c = lane << 1;
    size_t base = (size_t)n * DD + c;

    float di = dinv[n];
    unsigned hv = *reinterpret_cast<const unsigned*>(&Hb[base]);
    float s2 = 2.f * di * di;
    float sx = s2 * bf2f((unsigned short)(hv & 0xffff));
    float sy = s2 * bf2f((unsigned short)(hv >> 16));
    float ax = 0.f, ay = 0.f;  // edge accumulation (di applied at end)

    int e = rowp[n], e1 = rowp[n + 1];
    for (; e + 8 <= e1; e += 8) {
        int s[8];
        float w[8];
        unsigned gg[8];
        #pragma unroll
        for (int j = 0; j < 8; ++j) s[j] = col[e + j];
        #pragma unroll
        for (int j = 0; j < 8; ++j) w[j] = dinv[s[j]];
        #pragma unroll
        for (int j = 0; j < 8; ++j)
            gg[j] = *reinterpret_cast<const unsigned*>(&Hb[(size_t)s[j] * DD + c]);
        #pragma unroll
        for (int j = 0; j < 8; ++j) {
            ax += w[j] * bf2f((unsigned short)(gg[j] & 0xffff));
            ay += w[j] * bf2f((unsigned short)(gg[j] >> 16));
        }
    }
    for (; e + 2 <= e1; e += 2) {
        int s0 = col[e], s1 = col[e + 1];
        float w0 = dinv[s0], w1 = dinv[s1];
        unsigned g0 = *reinterpret_cast<const unsigned*>(&Hb[(size_t)s0 * DD + c]);
        unsigned g1 = *reinterpret_cast<const unsigned*>(&Hb[(size_t)s1 * DD + c]);
        ax += w0 * bf2f((unsigned short)(g0 & 0xffff)) + w1 * bf2f((unsigned short)(g1 & 0xffff));
        ay += w0 * bf2f((unsigned short)(g0 >> 16))    + w1 * bf2f((unsigned short)(g1 >> 16));
    }
    if (e < e1) {
        int s0 = col[e];
        float w0 = dinv[s0];
        unsigned g0 = *reinterpret_cast<const unsigned*>(&Hb[(size_t)s0 * DD + c]);
        ax += w0 * bf2f((unsigned short)(g0 & 0xffff));
        ay += w0 * bf2f((unsigned short)(g0 >> 16));
    }

    float2 bv = *reinterpret_cast<const float2*>(&bias[c]);
    float2 fv = *reinterpret_cast<const float2*>(&F[base]);
    float ox = di * ax + sx + bv.x + fv.x;
    float oy = di * ay + sy + bv.y + fv.y;
    if (addX) {
        float2 xv = *reinterpret_cast<const float2*>(&X[base]);
        ox += xv.x;
        oy += xv.y;
    }
    float2 o;
    o.x = ox;
    o.y = oy;
    *reinterpret_cast<float2*>(&OUT[base]) = o;
}

// ---------------- launch ----------------

extern "C" void kernel_launch(void* const* d_in, const int* in_sizes, int n_in,
                              void* d_out, int out_size, void* d_ws, size_t ws_size,
                              hipStream_t stream) {
    const float* x  = (const float*)d_in[0];
    const int*   ei = (const int*)d_in[1];
    const float* W0 = (const float*)d_in[2];
    const float* b0 = (const float*)d_in[3];
    const float* W1 = (const float*)d_in[4];
    const float* b1 = (const float*)d_in[5];
    const float* W2 = (const float*)d_in[6];
    const float* b2 = (const float*)d_in[7];
    float* out = (float*)d_out;

    const int N = NN, E = NE;
    const int* srcA = ei;       // edge_index[0]
    const int* dstA = ei + E;   // edge_index[1]

    char* ws = (char*)d_ws;
    size_t off = 0;
    auto alloc = [&](size_t bytes) -> char* {
        char* p = ws + off;
        off += (bytes + 255) & ~size_t(255);
        return p;
    };
    int*   rowp   = (int*)  alloc((size_t)(N + 1) * sizeof(int));
    int*   bcur   = (int*)  alloc(1024 * sizeof(int));
    int*   bsum   = (int*)  alloc(512 * sizeof(int));
    float* dinv   = (float*)alloc((size_t)N * sizeof(float));
    int*   col    = (int*)  alloc((size_t)E * sizeof(int));
    unsigned short* wt = (unsigned short*)alloc(3 * 32768);
    // tmp (k_part/k_place only) and h (gemm/agg only) never live at the same time
    size_t tmpBytes = (size_t)E * sizeof(uint2);
    size_t hBytes   = (size_t)N * DD * sizeof(unsigned short);
    char*  uni = alloc(tmpBytes > hBytes ? tmpBytes : hBytes);
    uint2* tmp = (uint2*)uni;
    unsigned short* h = (unsigned short*)uni;
    (void)ws_size; (void)in_sizes; (void)n_in; (void)out_size;

    hipMemsetAsync(rowp, 0, (size_t)(N + 1) * sizeof(int), stream);

    int gE = (E + 255) / 256;     // 6250
    int gN = (N + 255) / 256;     // 391
    int NB = (N + 127) / 128;     // 782 buckets
    k_count<<<gE, 256, 0, stream>>>(dstA, rowp + 1, E);
    k_prep <<<192, 256, 0, stream>>>(W0, W1, W2, wt);
    k_dinv <<<gN, 256, 0, stream>>>(rowp, dinv, N);
    k_scan1<<<gN, 256, 0, stream>>>(rowp, bsum, N);
    k_scan2<<<1, 512, 0, stream>>>(bsum, gN);
    k_scan3<<<gN, 256, 0, stream>>>(rowp, bsum, bcur, N);
    k_part <<<512, 256, 0, stream>>>(srcA, dstA, bcur, tmp, E, NB);
    k_place<<<NB, 256, 0, stream>>>(tmp, rowp, col, N);

    int gG = (N + 127) / 128;  // 782
    int gA = (N + 3) / 4;      // 25000

    // layer 0: F = x -> out
    k_gemm<<<gG, 512, 0, stream>>>(x, wt, h, N);
    k_agg <<<gA, 256, 0, stream>>>(h, rowp, col, dinv, b0, x, nullptr, out, N, 0);
    // layer 1: F = out -> out (in-place safe: each row read only by its own wave)
    k_gemm<<<gG, 512, 0, stream>>>(out, wt + 16384, h, N);
    k_agg <<<gA, 256, 0, stream>>>(h, rowp, col, dinv, b1, out, nullptr, out, N, 0);
    // layer 2: F = out -> out, plus global residual x
    k_gemm<<<gG, 512, 0, stream>>>(out, wt + 32768, h, N);
    k_agg <<<gA, 256, 0, stream>>>(h, rowp, col, dinv, b2, out, x, out, N, 1);
}

// Round 14
// 383.921 us; speedup vs baseline: 2.2048x; 1.0541x over previous
//
#include <hip/hip_runtime.h>

#define NN 100000
#define NE 1600000
#define DD 128

typedef short short8 __attribute__((ext_vector_type(8)));
typedef float f32x4 __attribute__((ext_vector_type(4)));

// ---------------- bf16 helpers ----------------

__device__ __forceinline__ unsigned short f2bf(float f) {
    union { float f; unsigned u; } v; v.f = f;
    unsigned r = v.u + 0x7FFF + ((v.u >> 16) & 1);  // round-to-nearest-even
    return (unsigned short)(r >> 16);
}
__device__ __forceinline__ float bf2f(unsigned short b) {
    union { unsigned u; float f; } v; v.u = (unsigned)b << 16;
    return v.f;
}

// ---------------- CSR construction ----------------

__global__ __launch_bounds__(256) void k_count(const int* __restrict__ dstA,
                                               int* __restrict__ cnt, int E) {
    int i = blockIdx.x * 256 + threadIdx.x;
    if (i < E) atomicAdd(&cnt[dstA[i]], 1);
}

// scan over counts; also emits dinv[i] = rsqrt(2 + cnt) (self-loop weight 2.0)
__global__ __launch_bounds__(256) void k_scan1(int* __restrict__ rowp,
                                               float* __restrict__ dinv,
                                               int* __restrict__ bsum, int N) {
    __shared__ int sm[256];
    int tid = threadIdx.x;
    int i = blockIdx.x * 256 + tid;
    int v = (i < N) ? rowp[1 + i] : 0;
    if (i < N) dinv[i] = rsqrtf(2.0f + (float)v);
    sm[tid] = v;
    #pragma unroll
    for (int off = 1; off < 256; off <<= 1) {
        __syncthreads();
        int t = (tid >= off) ? sm[tid - off] : 0;
        __syncthreads();
        sm[tid] += t;
    }
    if (i < N) rowp[1 + i] = sm[tid];
    if (tid == 255) bsum[blockIdx.x] = sm[255];
}

__global__ __launch_bounds__(512) void k_scan2(int* __restrict__ bsum, int nb) {
    __shared__ int sm[512];
    int tid = threadIdx.x;
    sm[tid] = (tid < nb) ? bsum[tid] : 0;
    #pragma unroll
    for (int off = 1; off < 512; off <<= 1) {
        __syncthreads();
        int t = (tid >= off) ? sm[tid - off] : 0;
        __syncthreads();
        sm[tid] += t;
    }
    if (tid < nb) bsum[tid] = sm[tid];
}

// finalize rowp; emit per-bucket (128 nodes) start cursors for the partition pass
__global__ __launch_bounds__(256) void k_scan3(int* __restrict__ rowp,
                                               const int* __restrict__ bsum,
                                               int* __restrict__ bcur, int N) {
    int tid = threadIdx.x;
    int i = blockIdx.x * 256 + tid;
    if (i >= N) return;
    int add = (blockIdx.x > 0) ? bsum[blockIdx.x - 1] : 0;
    int fin = rowp[1 + i] + add;
    rowp[1 + i] = fin;
    if (i == 0) bcur[0] = 0;
    if (((i + 1) & 127) == 0 && (i + 1) < N) bcur[(i + 1) >> 7] = fin;
}

// phase 1: chunked bucketing with block-aggregated atomics.
__global__ __launch_bounds__(256) void k_part(const int* __restrict__ srcA,
                                              const int* __restrict__ dstA,
                                              int* __restrict__ bcur,
                                              uint2* __restrict__ tmp, int E, int NBk) {
    __shared__ int cur[1024];
    int tid = threadIdx.x;
    int chunk = (E + gridDim.x - 1) / gridDim.x;
    int e0 = blockIdx.x * chunk;
    int e1 = e0 + chunk; e1 = e1 < E ? e1 : E;
    if (e0 >= e1) return;

    for (int b = tid; b < NBk; b += 256) cur[b] = 0;
    __syncthreads();
    for (int i = e0 + tid; i < e1; i += 256)
        atomicAdd(&cur[dstA[i] >> 7], 1);
    __syncthreads();
    for (int b = tid; b < NBk; b += 256) {
        int c = cur[b];
        cur[b] = (c > 0) ? atomicAdd(&bcur[b], c) : 0;
    }
    __syncthreads();
    for (int i = e0 + tid; i < e1; i += 256) {
        int s = srcA[i], d = dstA[i];
        int slot = atomicAdd(&cur[d >> 7], 1);
        uint2 p; p.x = (unsigned)s; p.y = (unsigned)d;
        tmp[slot] = p;
    }
}

// phase 2: exact CSR placement within each bucket via LDS cursors
__global__ __launch_bounds__(256) void k_place(const uint2* __restrict__ tmp,
                                               const int* __restrict__ rowp,
                                               int* __restrict__ col, int N) {
    __shared__ int lcur[128];
    int b = blockIdx.x;
    int n0 = b << 7;
    int tid = threadIdx.x;
    int nEnd = n0 + 128; nEnd = nEnd < N ? nEnd : N;
    int base = rowp[n0];
    int cnt = rowp[nEnd] - base;
    if (tid < 128) {
        int node = n0 + tid;
        lcur[tid] = (node < N) ? (rowp[node] - base) : 0;
    }
    __syncthreads();
    for (int i = tid; i < cnt; i += 256) {
        uint2 p = tmp[base + i];
        int j = (int)p.y - n0;
        int slot = atomicAdd(&lcur[j], 1);
        col[base + slot] = (int)p.x;
    }
}

// ---------------- W preparation: fp32 W[k][n] -> global swizzled bf16 (all 3 layers) ----------------
__global__ __launch_bounds__(256) void k_prep(const float* __restrict__ W0,
                                              const float* __restrict__ W1,
                                              const float* __restrict__ W2,
                                              unsigned short* __restrict__ wt) {
    int layer = blockIdx.x >> 6;
    int idx = (blockIdx.x & 63) * 256 + threadIdx.x;   // 0..16383
    const float* W = (layer == 0) ? W0 : (layer == 1) ? W1 : W2;
    char* dstB = (char*)(wt + (size_t)layer * 16384);
    int k = idx >> 7, n = idx & 127;
    int ba = (n * 256 + 2 * k) ^ ((n & 7) << 4);
    *(unsigned short*)(dstB + ba) = f2bf(W[idx]);
}

// ---------------- dense transform: Hb = bf16(A @ bf16(W)), MFMA ----------------
// BF16A=0: A rows are fp32 (converted per-fragment). BF16A=1: A rows are bf16
// (fragment = one 16B load). block = 512 (8 waves); 128 rows x 128 cols per block.
// LDS 34816B: [0,32KB) swizzled W during MFMA; reused as [128][272B] D-tile for epilogue.

template <int BF16A>
__global__ __launch_bounds__(512) void k_gemm(const void* __restrict__ Fv,
                                              const unsigned short* __restrict__ wt,
                                              unsigned short* __restrict__ Hb, int N) {
    __shared__ char Wl[34816];
    int tid = threadIdx.x;

    {   // stage 32KB (2048 uint4), 4 per thread
        const uint4* src = reinterpret_cast<const uint4*>(wt);
        uint4* dst = reinterpret_cast<uint4*>(Wl);
        #pragma unroll
        for (int i = 0; i < 4; ++i) dst[tid + 512 * i] = src[tid + 512 * i];
    }
    __syncthreads();

    int wv = tid >> 6;       // wave 0..7
    int l  = tid & 63;
    int nn = l & 15;         // A row / B col / D col within tile
    int g  = l >> 4;         // k-subgroup (and D row group)
    int r0w = blockIdx.x * 128 + wv * 16;

    int row = r0w + nn;
    row = row < N ? row : N - 1;  // clamp (stores guarded)

    f32x4 acc[8];
    #pragma unroll
    for (int nt = 0; nt < 8; ++nt) acc[nt] = (f32x4){0.f, 0.f, 0.f, 0.f};

    #pragma unroll
    for (int ks = 0; ks < 4; ++ks) {
        short8 a;
        if (BF16A) {
            const char* Fb = (const char*)Fv + (size_t)row * 256;
            a = *(const short8*)(Fb + ks * 64 + g * 16);
        } else {
            const float4* Fr = reinterpret_cast<const float4*>((const float*)Fv + (size_t)row * DD);
            float4 f0 = Fr[ks * 8 + g * 2];
            float4 f1 = Fr[ks * 8 + g * 2 + 1];
            a[0] = (short)f2bf(f0.x); a[1] = (short)f2bf(f0.y);
            a[2] = (short)f2bf(f0.z); a[3] = (short)f2bf(f0.w);
            a[4] = (short)f2bf(f1.x); a[5] = (short)f2bf(f1.y);
            a[6] = (short)f2bf(f1.z); a[7] = (short)f2bf(f1.w);
        }
        #pragma unroll
        for (int nt = 0; nt < 8; ++nt) {
            int ba = ((nt * 16 + nn) * 256 + ks * 64 + g * 16) ^ ((nn & 7) << 4);
            short8 b = *(const short8*)(Wl + ba);
            acc[nt] = __builtin_amdgcn_mfma_f32_16x16x32_bf16(a, b, acc[nt], 0, 0, 0);
        }
    }

    __syncthreads();  // all waves done reading W -> Wl reusable

    // stage D tile into LDS: row stride 272B (rotates banks by 4/row)
    #pragma unroll
    for (int nt = 0; nt < 8; ++nt) {
        #pragma unroll
        for (int j = 0; j < 4; ++j) {
            int r = wv * 16 + 4 * g + j;
            *(unsigned short*)(Wl + r * 272 + (nt * 16 + nn) * 2) = f2bf(acc[nt][j]);
        }
    }
    __syncthreads();

    // coalesced writeback: 2048 uint4 chunks (128 rows x 16 chunks), 4 per thread
    #pragma unroll
    for (int it = 0; it < 4; ++it) {
        int idx = it * 512 + tid;
        int r = idx >> 4, ch = idx & 15;
        int gr = blockIdx.x * 128 + r;
        if (gr < N) {
            uint4 v = *(const uint4*)(Wl + r * 272 + ch * 16);
            *reinterpret_cast<uint4*>(&Hb[(size_t)gr * DD + ch * 8]) = v;
        }
    }
}

// ---------------- aggregation (round-5 gather core; templated residual/out dtypes) ----------------
// OUT[n] = dinv[n] * sum_e dinv[col[e]]*Hb[col[e]] + 2*dinv[n]^2*Hb[n] + b + RES[n] (+X[n])

template <int RBF16, int OBF16, int ADDX>
__global__ __launch_bounds__(256) void k_agg(const unsigned short* __restrict__ Hb,
                                             const int* __restrict__ rowp,
                                             const int* __restrict__ col,
                                             const float* __restrict__ dinv,
                                             const float* __restrict__ bias,
                                             const void* __restrict__ resv,
                                             const float* __restrict__ X,
                                             void* __restrict__ outv, int N) {
    int lane = threadIdx.x & 63;
    int n = (blockIdx.x << 2) + (threadIdx.x >> 6);
    if (n >= N) return;
    int c = lane << 1;
    size_t base = (size_t)n * DD + c;

    float di = dinv[n];
    unsigned hv = *reinterpret_cast<const unsigned*>(&Hb[base]);
    float s2 = 2.f * di * di;
    float sx = s2 * bf2f((unsigned short)(hv & 0xffff));
    float sy = s2 * bf2f((unsigned short)(hv >> 16));
    float ax = 0.f, ay = 0.f;  // edge accumulation (di applied at end)

    int e = rowp[n], e1 = rowp[n + 1];
    for (; e + 8 <= e1; e += 8) {
        int s[8];
        float w[8];
        unsigned gg[8];
        #pragma unroll
        for (int j = 0; j < 8; ++j) s[j] = col[e + j];
        #pragma unroll
        for (int j = 0; j < 8; ++j) w[j] = dinv[s[j]];
        #pragma unroll
        for (int j = 0; j < 8; ++j)
            gg[j] = *reinterpret_cast<const unsigned*>(&Hb[(size_t)s[j] * DD + c]);
        #pragma unroll
        for (int j = 0; j < 8; ++j) {
            ax += w[j] * bf2f((unsigned short)(gg[j] & 0xffff));
            ay += w[j] * bf2f((unsigned short)(gg[j] >> 16));
        }
    }
    for (; e + 2 <= e1; e += 2) {
        int s0 = col[e], s1 = col[e + 1];
        float w0 = dinv[s0], w1 = dinv[s1];
        unsigned g0 = *reinterpret_cast<const unsigned*>(&Hb[(size_t)s0 * DD + c]);
        unsigned g1 = *reinterpret_cast<const unsigned*>(&Hb[(size_t)s1 * DD + c]);
        ax += w0 * bf2f((unsigned short)(g0 & 0xffff)) + w1 * bf2f((unsigned short)(g1 & 0xffff));
        ay += w0 * bf2f((unsigned short)(g0 >> 16))    + w1 * bf2f((unsigned short)(g1 >> 16));
    }
    if (e < e1) {
        int s0 = col[e];
        float w0 = dinv[s0];
        unsigned g0 = *reinterpret_cast<const unsigned*>(&Hb[(size_t)s0 * DD + c]);
        ax += w0 * bf2f((unsigned short)(g0 & 0xffff));
        ay += w0 * bf2f((unsigned short)(g0 >> 16));
    }

    float rx, ry;
    if (RBF16) {
        const unsigned short* R = (const unsigned short*)resv;
        unsigned rv = *reinterpret_cast<const unsigned*>(&R[base]);
        rx = bf2f((unsigned short)(rv & 0xffff));
        ry = bf2f((unsigned short)(rv >> 16));
    } else {
        const float* R = (const float*)resv;
        float2 fv = *reinterpret_cast<const float2*>(&R[base]);
        rx = fv.x; ry = fv.y;
    }
    float2 bv = *reinterpret_cast<const float2*>(&bias[c]);
    float ox = di * ax + sx + bv.x + rx;
    float oy = di * ay + sy + bv.y + ry;
    if (ADDX) {
        float2 xv = *reinterpret_cast<const float2*>(&X[base]);
        ox += xv.x;
        oy += xv.y;
    }
    if (OBF16) {
        unsigned short* O = (unsigned short*)outv;
        unsigned pv = (unsigned)f2bf(ox) | ((unsigned)f2bf(oy) << 16);
        *reinterpret_cast<unsigned*>(&O[base]) = pv;
    } else {
        float* O = (float*)outv;
        float2 o; o.x = ox; o.y = oy;
        *reinterpret_cast<float2*>(&O[base]) = o;
    }
}

// ---------------- launch ----------------

extern "C" void kernel_launch(void* const* d_in, const int* in_sizes, int n_in,
                              void* d_out, int out_size, void* d_ws, size_t ws_size,
                              hipStream_t stream) {
    const float* x  = (const float*)d_in[0];
    const int*   ei = (const int*)d_in[1];
    const float* W0 = (const float*)d_in[2];
    const float* b0 = (const float*)d_in[3];
    const float* W1 = (const float*)d_in[4];
    const float* b1 = (const float*)d_in[5];
    const float* W2 = (const float*)d_in[6];
    const float* b2 = (const float*)d_in[7];
    float* out = (float*)d_out;

    const int N = NN, E = NE;
    const int* srcA = ei;       // edge_index[0]
    const int* dstA = ei + E;   // edge_index[1]

    char* ws = (char*)d_ws;
    size_t off = 0;
    auto alloc = [&](size_t bytes) -> char* {
        char* p = ws + off;
        off += (bytes + 255) & ~size_t(255);
        return p;
    };
    int*   rowp   = (int*)  alloc((size_t)(N + 1) * sizeof(int));
    int*   bcur   = (int*)  alloc(1024 * sizeof(int));
    int*   bsum   = (int*)  alloc(512 * sizeof(int));
    float* dinv   = (float*)alloc((size_t)N * sizeof(float));
    int*   col    = (int*)  alloc((size_t)E * sizeof(int));
    unsigned short* wt = (unsigned short*)alloc(3 * 32768);
    unsigned short* ob = (unsigned short*)alloc((size_t)N * DD * sizeof(unsigned short));
    // tmp (k_part/k_place only) and h (gemm/agg only) never live at the same time
    size_t tmpBytes = (size_t)E * sizeof(uint2);
    size_t hBytes   = (size_t)N * DD * sizeof(unsigned short);
    char*  uni = alloc(tmpBytes > hBytes ? tmpBytes : hBytes);
    uint2* tmp = (uint2*)uni;
    unsigned short* h = (unsigned short*)uni;
    (void)ws_size; (void)in_sizes; (void)n_in; (void)out_size;

    hipMemsetAsync(rowp, 0, (size_t)(N + 1) * sizeof(int), stream);

    int gE = (E + 255) / 256;     // 6250
    int gN = (N + 255) / 256;     // 391
    int NB = (N + 127) / 128;     // 782 buckets
    k_count<<<gE, 256, 0, stream>>>(dstA, rowp + 1, E);
    k_prep <<<192, 256, 0, stream>>>(W0, W1, W2, wt);
    k_scan1<<<gN, 256, 0, stream>>>(rowp, dinv, bsum, N);
    k_scan2<<<1, 512, 0, stream>>>(bsum, gN);
    k_scan3<<<gN, 256, 0, stream>>>(rowp, bsum, bcur, N);
    k_part <<<512, 256, 0, stream>>>(srcA, dstA, bcur, tmp, E, NB);
    k_place<<<NB, 256, 0, stream>>>(tmp, rowp, col, N);

    int gG = (N + 127) / 128;  // 782
    int gA = (N + 3) / 4;      // 25000

    // layer 0: A = x (fp32); residual x (fp32); out -> ob (bf16)
    k_gemm<0><<<gG, 512, 0, stream>>>(x, wt, h, N);
    k_agg<0, 1, 0><<<gA, 256, 0, stream>>>(h, rowp, col, dinv, b0, x, nullptr, ob, N);
    // layer 1: A = ob (bf16); residual ob; out -> ob (in-place safe per-wave)
    k_gemm<1><<<gG, 512, 0, stream>>>(ob, wt + 16384, h, N);
    k_agg<1, 1, 0><<<gA, 256, 0, stream>>>(h, rowp, col, dinv, b1, ob, nullptr, ob, N);
    // layer 2: A = ob (bf16); residual ob; plus global residual x (fp32); out -> d_out (fp32)
    k_gemm<1><<<gG, 512, 0, stream>>>(ob, wt + 32768, h, N);
    k_agg<1, 0, 1><<<gA, 256, 0, stream>>>(h, rowp, col, dinv, b2, ob, x, out, N);
}

// Round 15
// 331.343 us; speedup vs baseline: 2.5547x; 1.1587x over previous
//
#include <hip/hip_runtime.h>

#define NN 100000
#define NE 1600000
#define DD 128

typedef short short8 __attribute__((ext_vector_type(8)));
typedef float f32x4 __attribute__((ext_vector_type(4)));

// ---------------- bf16 helpers ----------------

__device__ __forceinline__ unsigned short f2bf(float f) {
    union { float f; unsigned u; } v; v.f = f;
    unsigned r = v.u + 0x7FFF + ((v.u >> 16) & 1);  // round-to-nearest-even
    return (unsigned short)(r >> 16);
}
__device__ __forceinline__ float bf2f(unsigned short b) {
    union { unsigned u; float f; } v; v.u = (unsigned)b << 16;
    return v.f;
}

// ---------------- CSR construction (bucket-level only; no node-wide passes) ----------------

// bucket histogram: LDS-aggregated, one global atomic per (block,bucket)
__global__ __launch_bounds__(256) void k_bhist(const int* __restrict__ dstA,
                                               int* __restrict__ bcnt, int E, int NBk) {
    __shared__ int h[1024];
    int tid = threadIdx.x;
    int chunk = (E + gridDim.x - 1) / gridDim.x;
    int e0 = blockIdx.x * chunk;
    int e1 = e0 + chunk; e1 = e1 < E ? e1 : E;
    for (int b = tid; b < NBk; b += 256) h[b] = 0;
    __syncthreads();
    for (int i = e0 + tid; i < e1; i += 256)
        atomicAdd(&h[dstA[i] >> 7], 1);
    __syncthreads();
    for (int b = tid; b < NBk; b += 256) {
        int c = h[b];
        if (c > 0) atomicAdd(&bcnt[b], c);
    }
}

// single-block scan over NBk buckets -> exclusive bbase; also seeds bcur
__global__ __launch_bounds__(1024) void k_bscan(const int* __restrict__ bcnt,
                                                int* __restrict__ bbase,
                                                int* __restrict__ bcur, int NBk, int E) {
    __shared__ int sm[1024];
    int tid = threadIdx.x;
    int own = (tid < NBk) ? bcnt[tid] : 0;
    sm[tid] = own;
    #pragma unroll
    for (int off = 1; off < 1024; off <<= 1) {
        __syncthreads();
        int t = (tid >= off) ? sm[tid - off] : 0;
        __syncthreads();
        sm[tid] += t;
    }
    __syncthreads();
    if (tid < NBk) {
        int ex = sm[tid] - own;
        bbase[tid] = ex;
        bcur[tid] = ex;
    }
    if (tid == 0) bbase[NBk] = E;
}

// phase 1: chunked bucketing with block-aggregated atomics.
__global__ __launch_bounds__(256) void k_part(const int* __restrict__ srcA,
                                              const int* __restrict__ dstA,
                                              int* __restrict__ bcur,
                                              uint2* __restrict__ tmp, int E, int NBk) {
    __shared__ int cur[1024];
    int tid = threadIdx.x;
    int chunk = (E + gridDim.x - 1) / gridDim.x;
    int e0 = blockIdx.x * chunk;
    int e1 = e0 + chunk; e1 = e1 < E ? e1 : E;
    if (e0 >= e1) return;

    for (int b = tid; b < NBk; b += 256) cur[b] = 0;
    __syncthreads();
    for (int i = e0 + tid; i < e1; i += 256)
        atomicAdd(&cur[dstA[i] >> 7], 1);
    __syncthreads();
    for (int b = tid; b < NBk; b += 256) {
        int c = cur[b];
        cur[b] = (c > 0) ? atomicAdd(&bcur[b], c) : 0;
    }
    __syncthreads();
    for (int i = e0 + tid; i < e1; i += 256) {
        int s = srcA[i], d = dstA[i];
        int slot = atomicAdd(&cur[d >> 7], 1);
        uint2 p; p.x = (unsigned)s; p.y = (unsigned)d;
        tmp[slot] = p;
    }
}

// phase 2: per bucket, derive node counts (LDS hist) -> dinv, rowp (LDS scan), place col.
__global__ __launch_bounds__(256) void k_place(const uint2* __restrict__ tmp,
                                               const int* __restrict__ bbase,
                                               int* __restrict__ rowp,
                                               float* __restrict__ dinv,
                                               int* __restrict__ col,
                                               int N, int NBk, int E) {
    __shared__ int hist[128];
    __shared__ int lcur[128];
    int b = blockIdx.x;
    int n0 = b << 7;
    int tid = threadIdx.x;
    int base = bbase[b];
    int cnt = bbase[b + 1] - base;

    if (tid < 128) hist[tid] = 0;
    __syncthreads();
    for (int i = tid; i < cnt; i += 256)
        atomicAdd(&hist[(int)tmp[base + i].y - n0], 1);
    __syncthreads();
    if (tid < 128) lcur[tid] = hist[tid];
    #pragma unroll
    for (int off = 1; off < 128; off <<= 1) {
        __syncthreads();
        int t = (tid >= off && tid < 128) ? lcur[tid - off] : 0;
        __syncthreads();
        if (tid < 128) lcur[tid] += t;
    }
    __syncthreads();
    int pref = 0;
    if (tid < 128) {
        pref = lcur[tid] - hist[tid];  // exclusive prefix within bucket
        int node = n0 + tid;
        if (node < N) {
            rowp[node] = base + pref;
            dinv[node] = rsqrtf(2.0f + (float)hist[tid]);  // self-loop weight 2.0
        }
    }
    __syncthreads();
    if (tid < 128) lcur[tid] = pref;
    if (b == NBk - 1 && tid == 0) rowp[N] = E;
    __syncthreads();
    for (int i = tid; i < cnt; i += 256) {
        uint2 p = tmp[base + i];
        int j = (int)p.y - n0;
        int slot = atomicAdd(&lcur[j], 1);
        col[base + slot] = (int)p.x;
    }
}

// ---------------- W preparation: fp32 W[k][n] -> global swizzled bf16 (all 3 layers) ----------------
__global__ __launch_bounds__(256) void k_prep(const float* __restrict__ W0,
                                              const float* __restrict__ W1,
                                              const float* __restrict__ W2,
                                              unsigned short* __restrict__ wt) {
    int layer = blockIdx.x >> 6;
    int idx = (blockIdx.x & 63) * 256 + threadIdx.x;   // 0..16383
    const float* W = (layer == 0) ? W0 : (layer == 1) ? W1 : W2;
    char* dstB = (char*)(wt + (size_t)layer * 16384);
    int k = idx >> 7, n = idx & 127;
    int ba = (n * 256 + 2 * k) ^ ((n & 7) << 4);
    *(unsigned short*)(dstB + ba) = f2bf(W[idx]);
}

// ---------------- dense transform: Hb = bf16(A @ bf16(W)), MFMA ----------------
template <int BF16A>
__global__ __launch_bounds__(512) void k_gemm(const void* __restrict__ Fv,
                                              const unsigned short* __restrict__ wt,
                                              unsigned short* __restrict__ Hb, int N) {
    __shared__ char Wl[34816];
    int tid = threadIdx.x;

    {   // stage 32KB (2048 uint4), 4 per thread
        const uint4* src = reinterpret_cast<const uint4*>(wt);
        uint4* dst = reinterpret_cast<uint4*>(Wl);
        #pragma unroll
        for (int i = 0; i < 4; ++i) dst[tid + 512 * i] = src[tid + 512 * i];
    }
    __syncthreads();

    int wv = tid >> 6;       // wave 0..7
    int l  = tid & 63;
    int nn = l & 15;         // A row / B col / D col within tile
    int g  = l >> 4;         // k-subgroup (and D row group)
    int r0w = blockIdx.x * 128 + wv * 16;

    int row = r0w + nn;
    row = row < N ? row : N - 1;  // clamp (stores guarded)

    f32x4 acc[8];
    #pragma unroll
    for (int nt = 0; nt < 8; ++nt) acc[nt] = (f32x4){0.f, 0.f, 0.f, 0.f};

    #pragma unroll
    for (int ks = 0; ks < 4; ++ks) {
        short8 a;
        if (BF16A) {
            const char* Fb = (const char*)Fv + (size_t)row * 256;
            a = *(const short8*)(Fb + ks * 64 + g * 16);
        } else {
            const float4* Fr = reinterpret_cast<const float4*>((const float*)Fv + (size_t)row * DD);
            float4 f0 = Fr[ks * 8 + g * 2];
            float4 f1 = Fr[ks * 8 + g * 2 + 1];
            a[0] = (short)f2bf(f0.x); a[1] = (short)f2bf(f0.y);
            a[2] = (short)f2bf(f0.z); a[3] = (short)f2bf(f0.w);
            a[4] = (short)f2bf(f1.x); a[5] = (short)f2bf(f1.y);
            a[6] = (short)f2bf(f1.z); a[7] = (short)f2bf(f1.w);
        }
        #pragma unroll
        for (int nt = 0; nt < 8; ++nt) {
            int ba = ((nt * 16 + nn) * 256 + ks * 64 + g * 16) ^ ((nn & 7) << 4);
            short8 b = *(const short8*)(Wl + ba);
            acc[nt] = __builtin_amdgcn_mfma_f32_16x16x32_bf16(a, b, acc[nt], 0, 0, 0);
        }
    }

    __syncthreads();  // all waves done reading W -> Wl reusable

    // stage D tile into LDS: row stride 272B (rotates banks by 4/row)
    #pragma unroll
    for (int nt = 0; nt < 8; ++nt) {
        #pragma unroll
        for (int j = 0; j < 4; ++j) {
            int r = wv * 16 + 4 * g + j;
            *(unsigned short*)(Wl + r * 272 + (nt * 16 + nn) * 2) = f2bf(acc[nt][j]);
        }
    }
    __syncthreads();

    // coalesced writeback: 2048 uint4 chunks (128 rows x 16 chunks), 4 per thread
    #pragma unroll
    for (int it = 0; it < 4; ++it) {
        int idx = it * 512 + tid;
        int r = idx >> 4, ch = idx & 15;
        int gr = blockIdx.x * 128 + r;
        if (gr < N) {
            uint4 v = *(const uint4*)(Wl + r * 272 + ch * 16);
            *reinterpret_cast<uint4*>(&Hb[(size_t)gr * DD + ch * 8]) = v;
        }
    }
}

// ---------------- aggregation (round-5 gather core; templated residual/out dtypes) ----------------
// OUT[n] = dinv[n] * sum_e dinv[col[e]]*Hb[col[e]] + 2*dinv[n]^2*Hb[n] + b + RES[n] (+X[n])

template <int RBF16, int OBF16, int ADDX>
__global__ __launch_bounds__(256) void k_agg(const unsigned short* __restrict__ Hb,
                                             const int* __restrict__ rowp,
                                             const int* __restrict__ col,
                                             const float* __restrict__ dinv,
                                             const float* __restrict__ bias,
                                             const void* __restrict__ resv,
                                             const float* __restrict__ X,
                                             void* __restrict__ outv, int N) {
    int lane = threadIdx.x & 63;
    int n = (blockIdx.x << 2) + (threadIdx.x >> 6);
    if (n >= N) return;
    int c = lane << 1;
    size_t base = (size_t)n * DD + c;

    float di = dinv[n];
    unsigned hv = *reinterpret_cast<const unsigned*>(&Hb[base]);
    float s2 = 2.f * di * di;
    float sx = s2 * bf2f((unsigned short)(hv & 0xffff));
    float sy = s2 * bf2f((unsigned short)(hv >> 16));
    float ax = 0.f, ay = 0.f;  // edge accumulation (di applied at end)

    int e = rowp[n], e1 = rowp[n + 1];
    for (; e + 8 <= e1; e += 8) {
        int s[8];
        float w[8];
        unsigned gg[8];
        #pragma unroll
        for (int j = 0; j < 8; ++j) s[j] = col[e + j];
        #pragma unroll
        for (int j = 0; j < 8; ++j) w[j] = dinv[s[j]];
        #pragma unroll
        for (int j = 0; j < 8; ++j)
            gg[j] = *reinterpret_cast<const unsigned*>(&Hb[(size_t)s[j] * DD + c]);
        #pragma unroll
        for (int j = 0; j < 8; ++j) {
            ax += w[j] * bf2f((unsigned short)(gg[j] & 0xffff));
            ay += w[j] * bf2f((unsigned short)(gg[j] >> 16));
        }
    }
    for (; e + 2 <= e1; e += 2) {
        int s0 = col[e], s1 = col[e + 1];
        float w0 = dinv[s0], w1 = dinv[s1];
        unsigned g0 = *reinterpret_cast<const unsigned*>(&Hb[(size_t)s0 * DD + c]);
        unsigned g1 = *reinterpret_cast<const unsigned*>(&Hb[(size_t)s1 * DD + c]);
        ax += w0 * bf2f((unsigned short)(g0 & 0xffff)) + w1 * bf2f((unsigned short)(g1 & 0xffff));
        ay += w0 * bf2f((unsigned short)(g0 >> 16))    + w1 * bf2f((unsigned short)(g1 >> 16));
    }
    if (e < e1) {
        int s0 = col[e];
        float w0 = dinv[s0];
        unsigned g0 = *reinterpret_cast<const unsigned*>(&Hb[(size_t)s0 * DD + c]);
        ax += w0 * bf2f((unsigned short)(g0 & 0xffff));
        ay += w0 * bf2f((unsigned short)(g0 >> 16));
    }

    float rx, ry;
    if (RBF16) {
        const unsigned short* R = (const unsigned short*)resv;
        unsigned rv = *reinterpret_cast<const unsigned*>(&R[base]);
        rx = bf2f((unsigned short)(rv & 0xffff));
        ry = bf2f((unsigned short)(rv >> 16));
    } else {
        const float* R = (const float*)resv;
        float2 fv = *reinterpret_cast<const float2*>(&R[base]);
        rx = fv.x; ry = fv.y;
    }
    float2 bv = *reinterpret_cast<const float2*>(&bias[c]);
    float ox = di * ax + sx + bv.x + rx;
    float oy = di * ay + sy + bv.y + ry;
    if (ADDX) {
        float2 xv = *reinterpret_cast<const float2*>(&X[base]);
        ox += xv.x;
        oy += xv.y;
    }
    if (OBF16) {
        unsigned short* O = (unsigned short*)outv;
        unsigned pv = (unsigned)f2bf(ox) | ((unsigned)f2bf(oy) << 16);
        *reinterpret_cast<unsigned*>(&O[base]) = pv;
    } else {
        float* O = (float*)outv;
        float2 o; o.x = ox; o.y = oy;
        *reinterpret_cast<float2*>(&O[base]) = o;
    }
}

// ---------------- launch ----------------

extern "C" void kernel_launch(void* const* d_in, const int* in_sizes, int n_in,
                              void* d_out, int out_size, void* d_ws, size_t ws_size,
                              hipStream_t stream) {
    const float* x  = (const float*)d_in[0];
    const int*   ei = (const int*)d_in[1];
    const float* W0 = (const float*)d_in[2];
    const float* b0 = (const float*)d_in[3];
    const float* W1 = (const float*)d_in[4];
    const float* b1 = (const float*)d_in[5];
    const float* W2 = (const float*)d_in[6];
    const float* b2 = (const float*)d_in[7];
    float* out = (float*)d_out;

    const int N = NN, E = NE;
    const int* srcA = ei;       // edge_index[0]
    const int* dstA = ei + E;   // edge_index[1]

    char* ws = (char*)d_ws;
    size_t off = 0;
    auto alloc = [&](size_t bytes) -> char* {
        char* p = ws + off;
        off += (bytes + 255) & ~size_t(255);
        return p;
    };
    int*   rowp   = (int*)  alloc((size_t)(N + 1) * sizeof(int));
    int*   bcnt   = (int*)  alloc(1024 * sizeof(int));
    int*   bbase  = (int*)  alloc(1025 * sizeof(int));
    int*   bcur   = (int*)  alloc(1024 * sizeof(int));
    float* dinv   = (float*)alloc((size_t)N * sizeof(float));
    int*   col    = (int*)  alloc((size_t)E * sizeof(int));
    unsigned short* wt = (unsigned short*)alloc(3 * 32768);
    unsigned short* ob = (unsigned short*)alloc((size_t)N * DD * sizeof(unsigned short));
    // tmp (k_part/k_place only) and h (gemm/agg only) never live at the same time
    size_t tmpBytes = (size_t)E * sizeof(uint2);
    size_t hBytes   = (size_t)N * DD * sizeof(unsigned short);
    char*  uni = alloc(tmpBytes > hBytes ? tmpBytes : hBytes);
    uint2* tmp = (uint2*)uni;
    unsigned short* h = (unsigned short*)uni;
    (void)ws_size; (void)in_sizes; (void)n_in; (void)out_size;

    const int NB = (N + 127) / 128;     // 782 buckets
    hipMemsetAsync(bcnt, 0, 1024 * sizeof(int), stream);

    k_prep <<<192, 256, 0, stream>>>(W0, W1, W2, wt);
    k_bhist<<<512, 256, 0, stream>>>(dstA, bcnt, E, NB);
    k_bscan<<<1, 1024, 0, stream>>>(bcnt, bbase, bcur, NB, E);
    k_part <<<512, 256, 0, stream>>>(srcA, dstA, bcur, tmp, E, NB);
    k_place<<<NB, 256, 0, stream>>>(tmp, bbase, rowp, dinv, col, N, NB, E);

    int gG = (N + 127) / 128;  // 782
    int gA = (N + 3) / 4;      // 25000

    // layer 0: A = x (fp32); residual x (fp32); out -> ob (bf16)
    k_gemm<0><<<gG, 512, 0, stream>>>(x, wt, h, N);
    k_agg<0, 1, 0><<<gA, 256, 0, stream>>>(h, rowp, col, dinv, b0, x, nullptr, ob, N);
    // layer 1: A = ob (bf16); residual ob; out -> ob (in-place safe per-wave)
    k_gemm<1><<<gG, 512, 0, stream>>>(ob, wt + 16384, h, N);
    k_agg<1, 1, 0><<<gA, 256, 0, stream>>>(h, rowp, col, dinv, b1, ob, nullptr, ob, N);
    // layer 2: A = ob (bf16); residual ob; plus global residual x (fp32); out -> d_out (fp32)
    k_gemm<1><<<gG, 512, 0, stream>>>(ob, wt + 32768, h, N);
    k_agg<1, 0, 1><<<gA, 256, 0, stream>>>(h, rowp, col, dinv, b2, ob, x, out, N);
}

// Round 16
// 325.578 us; speedup vs baseline: 2.5999x; 1.0177x over previous
//
#include <hip/hip_runtime.h>

#define NN 100000
#define NE 1600000
#define DD 128

typedef short short8 __attribute__((ext_vector_type(8)));
typedef float f32x4 __attribute__((ext_vector_type(4)));

// ---------------- bf16 helpers ----------------

__device__ __forceinline__ unsigned short f2bf(float f) {
    union { float f; unsigned u; } v; v.f = f;
    unsigned r = v.u + 0x7FFF + ((v.u >> 16) & 1);  // round-to-nearest-even
    return (unsigned short)(r >> 16);
}
__device__ __forceinline__ float bf2f(unsigned short b) {
    union { unsigned u; float f; } v; v.u = (unsigned)b << 16;
    return v.f;
}

// ---------------- fused W-prep + bucket histogram ----------------
// blocks [0,192): W-prep (fp32 W[k][n] -> swizzled bf16, 3 layers)
// blocks [192,192+512): bucket histogram (LDS-aggregated)

__global__ __launch_bounds__(256) void k_pre(const float* __restrict__ W0,
                                             const float* __restrict__ W1,
                                             const float* __restrict__ W2,
                                             unsigned short* __restrict__ wt,
                                             const int* __restrict__ dstA,
                                             int* __restrict__ bcnt, int E, int NBk) {
    __shared__ int h[1024];
    int tid = threadIdx.x;
    if (blockIdx.x < 192) {
        int layer = blockIdx.x >> 6;
        int idx = (blockIdx.x & 63) * 256 + tid;   // 0..16383
        const float* W = (layer == 0) ? W0 : (layer == 1) ? W1 : W2;
        char* dstB = (char*)(wt + (size_t)layer * 16384);
        int k = idx >> 7, n = idx & 127;
        int ba = (n * 256 + 2 * k) ^ ((n & 7) << 4);
        *(unsigned short*)(dstB + ba) = f2bf(W[idx]);
        return;
    }
    int bid = blockIdx.x - 192;                    // 0..511
    int chunk = (E + 511) / 512;
    int e0 = bid * chunk;
    int e1 = e0 + chunk; e1 = e1 < E ? e1 : E;
    for (int b = tid; b < NBk; b += 256) h[b] = 0;
    __syncthreads();
    for (int i = e0 + tid; i < e1; i += 256)
        atomicAdd(&h[dstA[i] >> 7], 1);
    __syncthreads();
    for (int b = tid; b < NBk; b += 256) {
        int c = h[b];
        if (c > 0) atomicAdd(&bcnt[b], c);
    }
}

// single-block scan over NBk buckets -> exclusive bbase; also seeds bcur
__global__ __launch_bounds__(1024) void k_bscan(const int* __restrict__ bcnt,
                                                int* __restrict__ bbase,
                                                int* __restrict__ bcur, int NBk, int E) {
    __shared__ int sm[1024];
    int tid = threadIdx.x;
    int own = (tid < NBk) ? bcnt[tid] : 0;
    sm[tid] = own;
    #pragma unroll
    for (int off = 1; off < 1024; off <<= 1) {
        __syncthreads();
        int t = (tid >= off) ? sm[tid - off] : 0;
        __syncthreads();
        sm[tid] += t;
    }
    __syncthreads();
    if (tid < NBk) {
        int ex = sm[tid] - own;
        bbase[tid] = ex;
        bcur[tid] = ex;
    }
    if (tid == 0) bbase[NBk] = E;
}

// phase 1: chunked bucketing with block-aggregated atomics.
// tmp entry = (src << 7) | (dst & 127)  -- 4 bytes/edge
__global__ __launch_bounds__(256) void k_part(const int* __restrict__ srcA,
                                              const int* __restrict__ dstA,
                                              int* __restrict__ bcur,
                                              unsigned* __restrict__ tmp, int E, int NBk) {
    __shared__ int cur[1024];
    int tid = threadIdx.x;
    int chunk = (E + gridDim.x - 1) / gridDim.x;
    int e0 = blockIdx.x * chunk;
    int e1 = e0 + chunk; e1 = e1 < E ? e1 : E;
    if (e0 >= e1) return;

    for (int b = tid; b < NBk; b += 256) cur[b] = 0;
    __syncthreads();
    for (int i = e0 + tid; i < e1; i += 256)
        atomicAdd(&cur[dstA[i] >> 7], 1);
    __syncthreads();
    for (int b = tid; b < NBk; b += 256) {
        int c = cur[b];
        cur[b] = (c > 0) ? atomicAdd(&bcur[b], c) : 0;
    }
    __syncthreads();
    for (int i = e0 + tid; i < e1; i += 256) {
        unsigned s = (unsigned)srcA[i];
        int d = dstA[i];
        int slot = atomicAdd(&cur[d >> 7], 1);
        tmp[slot] = (s << 7) | ((unsigned)d & 127u);
    }
}

// phase 2: per bucket, derive node counts (LDS hist) -> dinv, rowp (LDS scan), place col.
__global__ __launch_bounds__(256) void k_place(const unsigned* __restrict__ tmp,
                                               const int* __restrict__ bbase,
                                               int* __restrict__ rowp,
                                               float* __restrict__ dinv,
                                               int* __restrict__ col,
                                               int N, int NBk, int E) {
    __shared__ int hist[128];
    __shared__ int lcur[128];
    int b = blockIdx.x;
    int n0 = b << 7;
    int tid = threadIdx.x;
    int base = bbase[b];
    int cnt = bbase[b + 1] - base;

    if (tid < 128) hist[tid] = 0;
    __syncthreads();
    for (int i = tid; i < cnt; i += 256)
        atomicAdd(&hist[tmp[base + i] & 127u], 1);
    __syncthreads();
    if (tid < 128) lcur[tid] = hist[tid];
    #pragma unroll
    for (int off = 1; off < 128; off <<= 1) {
        __syncthreads();
        int t = (tid >= off && tid < 128) ? lcur[tid - off] : 0;
        __syncthreads();
        if (tid < 128) lcur[tid] += t;
    }
    __syncthreads();
    int pref = 0;
    if (tid < 128) {
        pref = lcur[tid] - hist[tid];  // exclusive prefix within bucket
        int node = n0 + tid;
        if (node < N) {
            rowp[node] = base + pref;
            dinv[node] = rsqrtf(2.0f + (float)hist[tid]);  // self-loop weight 2.0
        }
    }
    __syncthreads();
    if (tid < 128) lcur[tid] = pref;
    if (b == NBk - 1 && tid == 0) rowp[N] = E;
    __syncthreads();
    for (int i = tid; i < cnt; i += 256) {
        unsigned p = tmp[base + i];
        int j = (int)(p & 127u);
        int slot = atomicAdd(&lcur[j], 1);
        col[base + slot] = (int)(p >> 7);
    }
}

// ---------------- dense transform: Hb = bf16(A @ bf16(W)), MFMA ----------------
template <int BF16A>
__global__ __launch_bounds__(512) void k_gemm(const void* __restrict__ Fv,
                                              const unsigned short* __restrict__ wt,
                                              unsigned short* __restrict__ Hb, int N) {
    __shared__ char Wl[34816];
    int tid = threadIdx.x;

    {   // stage 32KB (2048 uint4), 4 per thread
        const uint4* src = reinterpret_cast<const uint4*>(wt);
        uint4* dst = reinterpret_cast<uint4*>(Wl);
        #pragma unroll
        for (int i = 0; i < 4; ++i) dst[tid + 512 * i] = src[tid + 512 * i];
    }
    __syncthreads();

    int wv = tid >> 6;       // wave 0..7
    int l  = tid & 63;
    int nn = l & 15;         // A row / B col / D col within tile
    int g  = l >> 4;         // k-subgroup (and D row group)
    int r0w = blockIdx.x * 128 + wv * 16;

    int row = r0w + nn;
    row = row < N ? row : N - 1;  // clamp (stores guarded)

    f32x4 acc[8];
    #pragma unroll
    for (int nt = 0; nt < 8; ++nt) acc[nt] = (f32x4){0.f, 0.f, 0.f, 0.f};

    #pragma unroll
    for (int ks = 0; ks < 4; ++ks) {
        short8 a;
        if (BF16A) {
            const char* Fb = (const char*)Fv + (size_t)row * 256;
            a = *(const short8*)(Fb + ks * 64 + g * 16);
        } else {
            const float4* Fr = reinterpret_cast<const float4*>((const float*)Fv + (size_t)row * DD);
            float4 f0 = Fr[ks * 8 + g * 2];
            float4 f1 = Fr[ks * 8 + g * 2 + 1];
            a[0] = (short)f2bf(f0.x); a[1] = (short)f2bf(f0.y);
            a[2] = (short)f2bf(f0.z); a[3] = (short)f2bf(f0.w);
            a[4] = (short)f2bf(f1.x); a[5] = (short)f2bf(f1.y);
            a[6] = (short)f2bf(f1.z); a[7] = (short)f2bf(f1.w);
        }
        #pragma unroll
        for (int nt = 0; nt < 8; ++nt) {
            int ba = ((nt * 16 + nn) * 256 + ks * 64 + g * 16) ^ ((nn & 7) << 4);
            short8 b = *(const short8*)(Wl + ba);
            acc[nt] = __builtin_amdgcn_mfma_f32_16x16x32_bf16(a, b, acc[nt], 0, 0, 0);
        }
    }

    __syncthreads();  // all waves done reading W -> Wl reusable

    // stage D tile into LDS: row stride 272B (rotates banks by 4/row)
    #pragma unroll
    for (int nt = 0; nt < 8; ++nt) {
        #pragma unroll
        for (int j = 0; j < 4; ++j) {
            int r = wv * 16 + 4 * g + j;
            *(unsigned short*)(Wl + r * 272 + (nt * 16 + nn) * 2) = f2bf(acc[nt][j]);
        }
    }
    __syncthreads();

    // coalesced writeback: 2048 uint4 chunks (128 rows x 16 chunks), 4 per thread
    #pragma unroll
    for (int it = 0; it < 4; ++it) {
        int idx = it * 512 + tid;
        int r = idx >> 4, ch = idx & 15;
        int gr = blockIdx.x * 128 + r;
        if (gr < N) {
            uint4 v = *(const uint4*)(Wl + r * 272 + ch * 16);
            *reinterpret_cast<uint4*>(&Hb[(size_t)gr * DD + ch * 8]) = v;
        }
    }
}

// ---------------- aggregation (round-5 gather core; templated residual/out dtypes) ----------------
// OUT[n] = dinv[n] * sum_e dinv[col[e]]*Hb[col[e]] + 2*dinv[n]^2*Hb[n] + b + RES[n] (+X[n])

template <int RBF16, int OBF16, int ADDX>
__global__ __launch_bounds__(256) void k_agg(const unsigned short* __restrict__ Hb,
                                             const int* __restrict__ rowp,
                                             const int* __restrict__ col,
                                             const float* __restrict__ dinv,
                                             const float* __restrict__ bias,
                                             const void* __restrict__ resv,
                                             const float* __restrict__ X,
                                             void* __restrict__ outv, int N) {
    int lane = threadIdx.x & 63;
    int n = (blockIdx.x << 2) + (threadIdx.x >> 6);
    if (n >= N) return;
    int c = lane << 1;
    size_t base = (size_t)n * DD + c;

    float di = dinv[n];
    unsigned hv = *reinterpret_cast<const unsigned*>(&Hb[base]);
    float s2 = 2.f * di * di;
    float sx = s2 * bf2f((unsigned short)(hv & 0xffff));
    float sy = s2 * bf2f((unsigned short)(hv >> 16));
    float ax = 0.f, ay = 0.f;  // edge accumulation (di applied at end)

    int e = rowp[n], e1 = rowp[n + 1];
    for (; e + 8 <= e1; e += 8) {
        int s[8];
        float w[8];
        unsigned gg[8];
        #pragma unroll
        for (int j = 0; j < 8; ++j) s[j] = col[e + j];
        #pragma unroll
        for (int j = 0; j < 8; ++j) w[j] = dinv[s[j]];
        #pragma unroll
        for (int j = 0; j < 8; ++j)
            gg[j] = *reinterpret_cast<const unsigned*>(&Hb[(size_t)s[j] * DD + c]);
        #pragma unroll
        for (int j = 0; j < 8; ++j) {
            ax += w[j] * bf2f((unsigned short)(gg[j] & 0xffff));
            ay += w[j] * bf2f((unsigned short)(gg[j] >> 16));
        }
    }
    for (; e + 2 <= e1; e += 2) {
        int s0 = col[e], s1 = col[e + 1];
        float w0 = dinv[s0], w1 = dinv[s1];
        unsigned g0 = *reinterpret_cast<const unsigned*>(&Hb[(size_t)s0 * DD + c]);
        unsigned g1 = *reinterpret_cast<const unsigned*>(&Hb[(size_t)s1 * DD + c]);
        ax += w0 * bf2f((unsigned short)(g0 & 0xffff)) + w1 * bf2f((unsigned short)(g1 & 0xffff));
        ay += w0 * bf2f((unsigned short)(g0 >> 16))    + w1 * bf2f((unsigned short)(g1 >> 16));
    }
    if (e < e1) {
        int s0 = col[e];
        float w0 = dinv[s0];
        unsigned g0 = *reinterpret_cast<const unsigned*>(&Hb[(size_t)s0 * DD + c]);
        ax += w0 * bf2f((unsigned short)(g0 & 0xffff));
        ay += w0 * bf2f((unsigned short)(g0 >> 16));
    }

    float rx, ry;
    if (RBF16) {
        const unsigned short* R = (const unsigned short*)resv;
        unsigned rv = *reinterpret_cast<const unsigned*>(&R[base]);
        rx = bf2f((unsigned short)(rv & 0xffff));
        ry = bf2f((unsigned short)(rv >> 16));
    } else {
        const float* R = (const float*)resv;
        float2 fv = *reinterpret_cast<const float2*>(&R[base]);
        rx = fv.x; ry = fv.y;
    }
    float2 bv = *reinterpret_cast<const float2*>(&bias[c]);
    float ox = di * ax + sx + bv.x + rx;
    float oy = di * ay + sy + bv.y + ry;
    if (ADDX) {
        float2 xv = *reinterpret_cast<const float2*>(&X[base]);
        ox += xv.x;
        oy += xv.y;
    }
    if (OBF16) {
        unsigned short* O = (unsigned short*)outv;
        unsigned pv = (unsigned)f2bf(ox) | ((unsigned)f2bf(oy) << 16);
        *reinterpret_cast<unsigned*>(&O[base]) = pv;
    } else {
        float* O = (float*)outv;
        float2 o; o.x = ox; o.y = oy;
        *reinterpret_cast<float2*>(&O[base]) = o;
    }
}

// ---------------- launch ----------------

extern "C" void kernel_launch(void* const* d_in, const int* in_sizes, int n_in,
                              void* d_out, int out_size, void* d_ws, size_t ws_size,
                              hipStream_t stream) {
    const float* x  = (const float*)d_in[0];
    const int*   ei = (const int*)d_in[1];
    const float* W0 = (const float*)d_in[2];
    const float* b0 = (const float*)d_in[3];
    const float* W1 = (const float*)d_in[4];
    const float* b1 = (const float*)d_in[5];
    const float* W2 = (const float*)d_in[6];
    const float* b2 = (const float*)d_in[7];
    float* out = (float*)d_out;

    const int N = NN, E = NE;
    const int* srcA = ei;       // edge_index[0]
    const int* dstA = ei + E;   // edge_index[1]

    char* ws = (char*)d_ws;
    size_t off = 0;
    auto alloc = [&](size_t bytes) -> char* {
        char* p = ws + off;
        off += (bytes + 255) & ~size_t(255);
        return p;
    };
    int*   rowp   = (int*)  alloc((size_t)(N + 1) * sizeof(int));
    int*   bcnt   = (int*)  alloc(1024 * sizeof(int));
    int*   bbase  = (int*)  alloc(1025 * sizeof(int));
    int*   bcur   = (int*)  alloc(1024 * sizeof(int));
    float* dinv   = (float*)alloc((size_t)N * sizeof(float));
    int*   col    = (int*)  alloc((size_t)E * sizeof(int));
    unsigned short* wt = (unsigned short*)alloc(3 * 32768);
    unsigned short* ob = (unsigned short*)alloc((size_t)N * DD * sizeof(unsigned short));
    // tmp (k_part/k_place only) and h (gemm/agg only) never live at the same time
    size_t tmpBytes = (size_t)E * sizeof(unsigned);
    size_t hBytes   = (size_t)N * DD * sizeof(unsigned short);
    char*  uni = alloc(tmpBytes > hBytes ? tmpBytes : hBytes);
    unsigned* tmp = (unsigned*)uni;
    unsigned short* h = (unsigned short*)uni;
    (void)ws_size; (void)in_sizes; (void)n_in; (void)out_size;

    const int NB = (N + 127) / 128;     // 782 buckets
    hipMemsetAsync(bcnt, 0, 1024 * sizeof(int), stream);

    k_pre  <<<192 + 512, 256, 0, stream>>>(W0, W1, W2, wt, dstA, bcnt, E, NB);
    k_bscan<<<1, 1024, 0, stream>>>(bcnt, bbase, bcur, NB, E);
    k_part <<<512, 256, 0, stream>>>(srcA, dstA, bcur, tmp, E, NB);
    k_place<<<NB, 256, 0, stream>>>(tmp, bbase, rowp, dinv, col, N, NB, E);

    int gG = (N + 127) / 128;  // 782
    int gA = (N + 3) / 4;      // 25000

    // layer 0: A = x (fp32); residual x (fp32); out -> ob (bf16)
    k_gemm<0><<<gG, 512, 0, stream>>>(x, wt, h, N);
    k_agg<0, 1, 0><<<gA, 256, 0, stream>>>(h, rowp, col, dinv, b0, x, nullptr, ob, N);
    // layer 1: A = ob (bf16); residual ob; out -> ob (in-place safe per-wave)
    k_gemm<1><<<gG, 512, 0, stream>>>(ob, wt + 16384, h, N);
    k_agg<1, 1, 0><<<gA, 256, 0, stream>>>(h, rowp, col, dinv, b1, ob, nullptr, ob, N);
    // layer 2: A = ob (bf16); residual ob; plus global residual x (fp32); out -> d_out (fp32)
    k_gemm<1><<<gG, 512, 0, stream>>>(ob, wt + 32768, h, N);
    k_agg<1, 0, 1><<<gA, 256, 0, stream>>>(h, rowp, col, dinv, b2, ob, x, out, N);
}